// Round 10
// baseline (4190.371 us; speedup 1.0000x reference)
//
#include <hip/hip_runtime.h>
#include <cstdint>

// LSTM LM: logits = LSTM(E[idx] @ Wi) @ Wo + bo
// B=16, S=256, D=256, H=512, 4H=2048, V=50257 (padded to 50304 = 393*128)
//
// Round-10: DUAL-PATH sync — L2-local fast path + MALL fallback (placement-safe).
//  - producers = blockIdx%16==0 (16 blocks, all ≡0 mod 8 -> same XCD if HW
//    round-robins blockIdx across XCDs). 4 waves = 4 vp each (r9 math verbatim).
//  - h and flags dual-written: sc0 (writer's L2; fast for co-located readers)
//    AND sc1 (MALL; correct for everyone). Readers poll flagL (sc0); stale-L2
//    readers can never false-positive (stale value < t), and every 4th poll
//    checks flagM (sc1) -> guaranteed progress under ANY placement (r7 lesson).
//    Fast detection proves shared L2 -> gather h from hsL (sc0); fallback ->
//    gather from hsP (sc1, the r2..r9-proven path).
//  - consumers (240 blocks): r8/r9 GEMM verbatim, gated on epC (sc1).

typedef __attribute__((ext_vector_type(8))) short short8;
typedef __attribute__((ext_vector_type(4))) float f32x4;
typedef __attribute__((ext_vector_type(4))) unsigned int u32x4;
typedef __attribute__((ext_vector_type(4))) unsigned short ush4;

#define DEVFN static __device__ __forceinline__

DEVFN unsigned short f2bf(float f) {
    unsigned int u = __float_as_uint(f);
    return (unsigned short)((u + 0x7FFFu + ((u >> 16) & 1u)) >> 16);  // RNE
}
DEVFN float bf2f(unsigned short h) { return __uint_as_float(((unsigned int)h) << 16); }
DEVFN float sigm(float x) { return 1.0f / (1.0f + __expf(-x)); }
DEVFN float tanh_fast(float x) {
    float e = __expf(-2.0f * fabsf(x));
    float t = (1.0f - e) / (1.0f + e);
    return copysignf(t, x);
}
DEVFN f32x4 fzero() { f32x4 v = {0.f, 0.f, 0.f, 0.f}; return v; }

// ---- L2-scope (sc0) ops: fast when producer+reader share an XCD L2 ----
DEVFN uint32_t ld_flag_l2(const uint32_t* p) {
    uint32_t v;
    asm volatile("global_load_dword %0, %1, off sc0\n\ts_waitcnt vmcnt(0)"
                 : "=v"(v) : "v"(p) : "memory");
    return v;
}
DEVFN void st_u32_l2(uint32_t* p, uint32_t v) {
    asm volatile("global_store_dword %0, %1, off sc0" :: "v"(p), "v"(v) : "memory");
}
DEVFN void aload16_l2(u32x4& d, const void* p) {
    asm volatile("global_load_dwordx4 %0, %1, off sc0" : "=v"(d) : "v"(p));
}
// ---- MALL-scope (sc0 sc1) ops: correct under any placement ----
DEVFN uint32_t ld_flag_mall(const uint32_t* p) {
    uint32_t v;
    asm volatile("global_load_dword %0, %1, off sc0 sc1\n\ts_waitcnt vmcnt(0)"
                 : "=v"(v) : "v"(p) : "memory");
    return v;
}
DEVFN void st_flag_mall(uint32_t* p, uint32_t v) {
    asm volatile("global_store_dword %0, %1, off sc0 sc1" :: "v"(p), "v"(v) : "memory");
}
DEVFN void st_u32_mall(uint32_t* p, uint32_t v) {
    asm volatile("global_store_dword %0, %1, off sc0 sc1" :: "v"(p), "v"(v) : "memory");
}
DEVFN void aload16(u32x4& d, const void* p) {
    asm volatile("global_load_dwordx4 %0, %1, off sc0 sc1" : "=v"(d) : "v"(p));
}

// ---------------- k0: transpose + split Wo -> WoTP[50304][512] packed u32 ----------------
__global__ __launch_bounds__(256) void k0_wot(const float* __restrict__ Wo,
                                              uint32_t* __restrict__ WoTP) {
    __shared__ float tile[32][33];
    const int bx = blockIdx.x;
    const int cb = bx >> 4;
    const int kb = bx & 15;
    const int c0 = cb * 32, k0 = kb * 32;
    const int j = threadIdx.x & 31;
    const int i0 = threadIdx.x >> 5;
    for (int ii = i0; ii < 32; ii += 8) {
        const int c = c0 + j;
        tile[ii][j] = (c < 50257) ? Wo[(size_t)(k0 + ii) * 50257 + c] : 0.0f;
    }
    __syncthreads();
    for (int ii = i0; ii < 32; ii += 8) {
        const float v = tile[j][ii];
        const unsigned short hi = f2bf(v);
        const unsigned short lo = f2bf(v - bf2f(hi));
        WoTP[(size_t)(c0 + ii) * 512 + k0 + j] = (((unsigned int)hi) << 16) | lo;
    }
}

// -------- k0b: Wh bf16 hi AND lo B-fragments: [vp][nt][q][lane] 16B each -----------------
__global__ __launch_bounds__(256) void k0b_whfrag(const float* __restrict__ Wh,
                                                  uint32_t* __restrict__ WHI,
                                                  uint32_t* __restrict__ WLO) {
    const int tid = blockIdx.x * 256 + threadIdx.x;   // 0..131071
    const int lane = tid & 63;
    const int q    = (tid >> 6) & 15;
    const int nt   = (tid >> 10) & 1;
    const int vp   = tid >> 11;          // virtual producer 0..63 (8 hidden units each)
    const int cc   = lane & 15;
    const int gcol = (cc >> 2) * 512 + vp * 8 + nt * 4 + (cc & 3);
    const int kbase = q * 32 + (lane >> 4) * 8;
    u32x4 ohi, olo;
#pragma unroll
    for (int p = 0; p < 4; ++p) {
        unsigned int phi = 0, plo = 0;
#pragma unroll
        for (int e = 0; e < 2; ++e) {
            const int k = kbase + p * 2 + e;
            const float w = Wh[(size_t)k * 2048 + gcol];
            const unsigned short hi = f2bf(w);
            const unsigned short lo = f2bf(w - bf2f(hi));
            phi |= ((unsigned int)hi) << (e * 16);
            plo |= ((unsigned int)lo) << (e * 16);
        }
        ohi[p] = phi; olo[p] = plo;
    }
    *(u32x4*)(WHI + (size_t)tid * 4) = ohi;
    *(u32x4*)(WLO + (size_t)tid * 4) = olo;
}

// ---------------- k1: xzH[s][b][g] = bf16( sum_d E[idx[b,s],d] * Wi[d,g] ) ---------------
__global__ __launch_bounds__(256) void k1_xz(const int* __restrict__ idx,
                                             const float* __restrict__ E,
                                             const float* __restrict__ Wi,
                                             unsigned short* __restrict__ xzH) {
    __shared__ float xs[16][256];
    const int s = blockIdx.x;
    const int t = threadIdx.x;
#pragma unroll
    for (int b = 0; b < 16; ++b) {
        const int row = idx[b * 256 + s];
        xs[b][t] = E[(size_t)row * 256 + t];
    }
    __syncthreads();
    for (int half = 0; half < 2; ++half) {
        const int g0 = half * 1024 + t * 4;
        f32x4 acc[16];
#pragma unroll
        for (int b = 0; b < 16; ++b) acc[b] = fzero();
        for (int d = 0; d < 256; ++d) {
            const f32x4 w = *(const f32x4*)&Wi[(size_t)d * 2048 + g0];
#pragma unroll
            for (int b = 0; b < 16; ++b) {
                const float xv = xs[b][d];
                acc[b] += xv * w;
            }
        }
#pragma unroll
        for (int b = 0; b < 16; ++b) {
            ush4 o;
#pragma unroll
            for (int jj = 0; jj < 4; ++jj) o[jj] = f2bf(acc[b][jj]);
            *(ush4*)&xzH[((size_t)s * 16 + b) * 2048 + g0] = o;
        }
    }
}

// ---------------- k23: fused recurrence (16 blocks) + consumer GEMM (240 blocks) ---------
__global__ __launch_bounds__(256, 1) void k23(const float* __restrict__ bh,
                                              const unsigned short* __restrict__ xzH,
                                              const short8* __restrict__ WHI8,
                                              const short8* __restrict__ WLO8,
                                              uint32_t* __restrict__ hsP,   // MALL h
                                              uint32_t* __restrict__ hsL,   // L2-local h
                                              uint32_t* __restrict__ flagL,
                                              uint32_t* __restrict__ flagM,
                                              uint32_t* __restrict__ epC,
                                              const uint32_t* __restrict__ WoTP,
                                              const float* __restrict__ bo,
                                              float* __restrict__ out) {
    __shared__ __align__(16) char smem[131072];   // 128KB -> 1 block/CU everywhere
    __shared__ unsigned int sfast;

    const int tid = threadIdx.x;

    if ((blockIdx.x & 15) == 0) {
        // ================= PRODUCER block: 4 frontier waves (vp = blk*4 + w) =============
        const int blk = blockIdx.x >> 4;   // 0..15
        const int w = tid >> 6;
        const int lane = tid & 63;
        const int vp = blk * 4 + w;
        const int c = lane & 15;
        const int qtr = lane >> 4;

        int gc[2];
        float bh_v[2];
#pragma unroll
        for (int nt = 0; nt < 2; ++nt) {
            gc[nt] = (c >> 2) * 512 + vp * 8 + nt * 4 + (c & 3);
            bh_v[nt] = bh[gc[nt]];
        }
        float cst[2][4];
#pragma unroll
        for (int nt = 0; nt < 2; ++nt)
#pragma unroll
            for (int r = 0; r < 4; ++r) cst[nt][r] = 0.0f;

        float xzv[2][4];
#pragma unroll
        for (int nt = 0; nt < 2; ++nt)
#pragma unroll
            for (int r = 0; r < 4; ++r)
                xzv[nt][r] = bf2f(xzH[(size_t)(qtr * 4 + r) * 2048 + gc[nt]]);

        short8 bz = {0, 0, 0, 0, 0, 0, 0, 0};
        f32x4 bd0 = fzero(), bd1 = fzero();
        if (tid == 0) sfast = 1u;

        for (int t = 0; t < 256; ++t) {
            if (t > 0) {
                // dual-path poll: sc0 fast (proves shared L2), sc1 fallback (liveness)
                int fast = 1;
                int it = 0;
                while (true) {
                    const uint32_t vL = ld_flag_l2(flagL + lane);
                    if (__all((int)(vL >= (uint32_t)t))) { fast = 1; break; }
                    if ((it & 3) == 3) {
                        const uint32_t vM = ld_flag_mall(flagM + lane);
                        const uint32_t mx = (vL > vM) ? vL : vM;
                        if (__all((int)(mx >= (uint32_t)t))) { fast = 0; break; }
                    }
#pragma unroll
                    for (int i = 0; i < 2; ++i) {
                        bd0 = __builtin_amdgcn_mfma_f32_16x16x32_bf16(bz, bz, bd0, 0, 0, 0);
                        bd1 = __builtin_amdgcn_mfma_f32_16x16x32_bf16(bz, bz, bd1, 0, 0, 0);
                    }
                    ++it;
                }
                if (w == 0 && lane == 0) {
                    sfast = (unsigned)fast;
                    if (blk == 0) st_flag_mall(epC, (uint32_t)t);
                }
                __builtin_amdgcn_sched_barrier(0);
            }
            __syncthreads();   // sfast published; prev-step LDS reads done

            // -------- cooperative h(t-1) gather -> LDS (one batched RT) --------
            if (t == 0) {
                const u32x4 z = {0u, 0u, 0u, 0u};
#pragma unroll
                for (int j = 0; j < 8; ++j) {
                    const int U = j * 256 + tid;
                    const int b = U >> 7, u = U & 127;
                    *(u32x4*)(smem + b * 2048 + ((u ^ (b & 7)) << 4)) = z;
                }
            } else {
                const bool f = (sfast != 0u);
                u32x4 gv[8];
                if (f) {
#pragma unroll
                    for (int j = 0; j < 8; ++j) {
                        const int U = j * 256 + tid;
                        const int b = U >> 7, u = U & 127;
                        aload16_l2(gv[j], hsL + ((size_t)(t - 1) * 16 + b) * 512 + u * 4);
                    }
                } else {
#pragma unroll
                    for (int j = 0; j < 8; ++j) {
                        const int U = j * 256 + tid;
                        const int b = U >> 7, u = U & 127;
                        aload16(gv[j], hsP + ((size_t)(t - 1) * 16 + b) * 512 + u * 4);
                    }
                }
                asm volatile("s_waitcnt vmcnt(0)" ::: "memory");
                __builtin_amdgcn_sched_barrier(0);
#pragma unroll
                for (int j = 0; j < 8; ++j) {
                    const int U = j * 256 + tid;
                    const int b = U >> 7, u = U & 127;
                    *(u32x4*)(smem + b * 2048 + ((u ^ (b & 7)) << 4)) = gv[j];
                }
            }
            __syncthreads();

            f32x4 acc[2][2];
#pragma unroll
            for (int nt = 0; nt < 2; ++nt) { acc[nt][0] = fzero(); acc[nt][1] = fzero(); }

#pragma unroll
            for (int q = 0; q < 16; ++q) {
                const int u0 = q * 8 + qtr * 2;
                const u32x4 h0 = *(const u32x4*)(smem + c * 2048 + ((u0 ^ (c & 7)) << 4));
                const u32x4 h1 = *(const u32x4*)(smem + c * 2048 + (((u0 + 1) ^ (c & 7)) << 4));
                short8 ahi, alo;
#pragma unroll
                for (int i = 0; i < 4; ++i) {
                    ahi[i]     = (short)(h0[i] >> 16); alo[i]     = (short)(h0[i] & 0xffffu);
                    ahi[4 + i] = (short)(h1[i] >> 16); alo[4 + i] = (short)(h1[i] & 0xffffu);
                }
#pragma unroll
                for (int nt = 0; nt < 2; ++nt) {
                    const short8 bhi = WHI8[(((size_t)vp * 2 + nt) * 16 + q) * 64 + lane];
                    const short8 blo = WLO8[(((size_t)vp * 2 + nt) * 16 + q) * 64 + lane];
                    f32x4 a = acc[nt][q & 1];
                    a = __builtin_amdgcn_mfma_f32_16x16x32_bf16(ahi, bhi, a, 0, 0, 0);
                    a = __builtin_amdgcn_mfma_f32_16x16x32_bf16(ahi, blo, a, 0, 0, 0);
                    a = __builtin_amdgcn_mfma_f32_16x16x32_bf16(alo, bhi, a, 0, 0, 0);
                    acc[nt][q & 1] = a;
                }
            }

#pragma unroll
            for (int nt = 0; nt < 2; ++nt) {
                f32x4 z4 = acc[nt][0] + acc[nt][1];
#pragma unroll
                for (int r = 0; r < 4; ++r) z4[r] += xzv[nt][r] + bh_v[nt];
#pragma unroll
                for (int r = 0; r < 4; ++r) {
                    const int sb = (lane & 0x33);
                    const float zi = __shfl(z4[r], sb);
                    const float zf = __shfl(z4[r], sb | 4);
                    const float zg = __shfl(z4[r], sb | 8);
                    const float zo = __shfl(z4[r], sb | 12);
                    const float iv = sigm(zi), fv = sigm(zf);
                    const float gv = tanh_fast(zg), ov = sigm(zo);
                    const float cv = fv * cst[nt][r] + iv * gv;
                    cst[nt][r] = cv;
                    const float hv = ov * tanh_fast(cv);
                    if ((c >> 2) == 0) {   // one owner lane per (b, j)
                        const unsigned short hi = f2bf(hv);
                        const unsigned short lo = f2bf(hv - bf2f(hi));
                        const uint32_t packed = (((uint32_t)hi) << 16) | lo;
                        const size_t ix =
                            ((size_t)t * 16 + qtr * 4 + r) * 512 + vp * 8 + nt * 4 + c;
                        st_u32_l2(&hsL[ix], packed);    // L2-local copy (fast path)
                        st_u32_mall(&hsP[ix], packed);  // MALL copy (always correct)
                    }
                }
            }

            // own h-stores (both paths) ACKed before flags become visible
            asm volatile("s_waitcnt vmcnt(0)" ::: "memory");
            if (lane == 0) {
                st_u32_l2(&flagL[vp], (uint32_t)(t + 1));
                st_flag_mall(&flagM[vp], (uint32_t)(t + 1));
            }

            if (t < 255) {
#pragma unroll
                for (int nt = 0; nt < 2; ++nt)
#pragma unroll
                    for (int r = 0; r < 4; ++r)
                        xzv[nt][r] = bf2f(xzH[((size_t)(t + 1) * 16 + qtr * 4 + r) * 2048 + gc[nt]]);
            }
        }

        // epilogue: block 0 wave 0 publishes final epoch (consumers' s0=31 needs 256)
        if (blk == 0 && w == 0) {
            const int lane0 = tid & 63;
            while (true) {
                const uint32_t vM = ld_flag_mall(flagM + lane0);
                if (__all((int)(vM >= 256u))) break;
            }
            if (lane0 == 0) st_flag_mall(epC, 256u);
        }
        asm volatile("" :: "v"(bd0), "v"(bd1));
    } else {
        // ================= CONSUMER (240 blocks): s0-outer / v-inner =====================
        unsigned short (*Ah)[64] = (unsigned short(*)[64])(smem);
        unsigned short (*Al)[64] = (unsigned short(*)[64])(smem + 16384);
        unsigned short (*Bh)[64] = (unsigned short(*)[64])(smem + 32768);
        unsigned short (*Bl)[64] = (unsigned short(*)[64])(smem + 49152);

        const int cid = blockIdx.x - 1 - (blockIdx.x >> 4);   // 0..239
        const int lane = tid & 63;
        const int wv = tid >> 6;
        const int wr = wv >> 1, wc = wv & 1;
        const int srow = tid >> 1, shalf = tid & 1;

        short8 bz = {0, 0, 0, 0, 0, 0, 0, 0};
        f32x4 bd0 = fzero(), bd1 = fzero(), bd2 = fzero(), bd3 = fzero();

        for (int s0 = 0; s0 < 32; ++s0) {
            const unsigned need = (unsigned)(s0 * 8 + 8);   // steps done required
            while (true) {
                const uint32_t f = ld_flag_mall(epC);       // uniform addr: 1 req/wave
                if (f >= need) break;
#pragma unroll
                for (int i = 0; i < 8; ++i) {
                    bd0 = __builtin_amdgcn_mfma_f32_16x16x32_bf16(bz, bz, bd0, 0, 0, 0);
                    bd1 = __builtin_amdgcn_mfma_f32_16x16x32_bf16(bz, bz, bd1, 0, 0, 0);
                    bd2 = __builtin_amdgcn_mfma_f32_16x16x32_bf16(bz, bz, bd2, 0, 0, 0);
                    bd3 = __builtin_amdgcn_mfma_f32_16x16x32_bf16(bz, bz, bd3, 0, 0, 0);
                }
            }

            for (int vi = 0; vi < 2; ++vi) {
                const int v = cid + vi * 240;
                if (v >= 393) break;

                f32x4 acc[4][4];
#pragma unroll
                for (int i = 0; i < 4; ++i)
#pragma unroll
                    for (int j = 0; j < 4; ++j) acc[i][j] = fzero();

                for (int kb = 0; kb < 8; ++kb) {
                    __syncthreads();
                    const uint32_t* sa = hsP + (size_t)(s0 * 128 + srow) * 512 + kb * 64 + shalf * 32;
                    const uint32_t* sbp = WoTP + (size_t)(v * 128 + srow) * 512 + kb * 64 + shalf * 32;
                    u32x4 av[8], bv[8];
#pragma unroll
                    for (int g = 0; g < 4; ++g) {
                        aload16(av[2 * g], sa + g * 8);
                        aload16(av[2 * g + 1], sa + g * 8 + 4);
                    }
#pragma unroll
                    for (int g = 0; g < 4; ++g) {
                        bv[2 * g]     = *(const u32x4*)(sbp + g * 8);
                        bv[2 * g + 1] = *(const u32x4*)(sbp + g * 8 + 4);
                    }
                    asm volatile("s_waitcnt vmcnt(0)" ::: "memory");
                    __builtin_amdgcn_sched_barrier(0);
#pragma unroll
                    for (int g = 0; g < 4; ++g) {
                        short8 hi, lo;
#pragma unroll
                        for (int i = 0; i < 4; ++i) {
                            hi[i]     = (short)(av[2 * g][i] >> 16);
                            lo[i]     = (short)(av[2 * g][i] & 0xffffu);
                            hi[4 + i] = (short)(av[2 * g + 1][i] >> 16);
                            lo[4 + i] = (short)(av[2 * g + 1][i] & 0xffffu);
                        }
                        const int sw = ((shalf * 4 + g) ^ (srow & 7)) << 4;
                        *(short8*)((char*)Ah + srow * 128 + sw) = hi;
                        *(short8*)((char*)Al + srow * 128 + sw) = lo;
                    }
#pragma unroll
                    for (int g = 0; g < 4; ++g) {
                        short8 hi, lo;
#pragma unroll
                        for (int i = 0; i < 4; ++i) {
                            hi[i]     = (short)(bv[2 * g][i] >> 16);
                            lo[i]     = (short)(bv[2 * g][i] & 0xffffu);
                            hi[4 + i] = (short)(bv[2 * g + 1][i] >> 16);
                            lo[4 + i] = (short)(bv[2 * g + 1][i] & 0xffffu);
                        }
                        const int sw = ((shalf * 4 + g) ^ (srow & 7)) << 4;
                        *(short8*)((char*)Bh + srow * 128 + sw) = hi;
                        *(short8*)((char*)Bl + srow * 128 + sw) = lo;
                    }
                    __syncthreads();

#pragma unroll
                    for (int q = 0; q < 2; ++q) {
                        short8 afh[4], afl[4], bfh[4], bfl[4];
#pragma unroll
                        for (int mi = 0; mi < 4; ++mi) {
                            const int r = wr * 64 + mi * 16 + (lane & 15);
                            const int sw = ((q * 4 + (lane >> 4)) ^ (r & 7)) << 4;
                            afh[mi] = *(const short8*)((const char*)Ah + r * 128 + sw);
                            afl[mi] = *(const short8*)((const char*)Al + r * 128 + sw);
                        }
#pragma unroll
                        for (int nj = 0; nj < 4; ++nj) {
                            const int r = wc * 64 + nj * 16 + (lane & 15);
                            const int sw = ((q * 4 + (lane >> 4)) ^ (r & 7)) << 4;
                            bfh[nj] = *(const short8*)((const char*)Bh + r * 128 + sw);
                            bfl[nj] = *(const short8*)((const char*)Bl + r * 128 + sw);
                        }
#pragma unroll
                        for (int mi = 0; mi < 4; ++mi)
#pragma unroll
                            for (int nj = 0; nj < 4; ++nj) {
                                f32x4 a = acc[mi][nj];
                                a = __builtin_amdgcn_mfma_f32_16x16x32_bf16(afh[mi], bfh[nj], a, 0, 0, 0);
                                a = __builtin_amdgcn_mfma_f32_16x16x32_bf16(afh[mi], bfl[nj], a, 0, 0, 0);
                                a = __builtin_amdgcn_mfma_f32_16x16x32_bf16(afl[mi], bfh[nj], a, 0, 0, 0);
                                acc[mi][nj] = a;
                            }
                    }
                }

#pragma unroll
                for (int nj = 0; nj < 4; ++nj) {
                    const int colg = v * 128 + wc * 64 + nj * 16 + (lane & 15);
                    if (colg < 50257) {
                        const float bov = bo[colg];
#pragma unroll
                        for (int mi = 0; mi < 4; ++mi)
#pragma unroll
                            for (int r = 0; r < 4; ++r) {
                                const int tr = wr * 64 + mi * 16 + (lane >> 4) * 4 + r;
                                const int ss = s0 * 8 + (tr >> 4);
                                const int bb = tr & 15;
                                out[((size_t)bb * 256 + ss) * 50257 + colg] = acc[mi][nj][r] + bov;
                            }
                    }
                }
            }
        }
        asm volatile("" :: "v"(bd0), "v"(bd1), "v"(bd2), "v"(bd3));
    }
}

// ---------------- launch ----------------------------------------------------------------
// Workspace (total ~141 MB <= proven-safe 147 MB):
#define XZH_OFF   0ull          // 256*16*2048*2  = 16,777,216  (bf16 xz)
#define HSP_OFF   16777216ull   // 256*16*512*4   =  8,388,608  (h, MALL path)
#define HSL_OFF   25165824ull   // 256*16*512*4   =  8,388,608  (h, L2-local path)
#define FLG_OFF   33554432ull   // 4096 B: flagL @ +0, flagM @ +512, epC @ +1024
#define WHI_OFF   33558528ull   // 64*2*16*64*16  =  2,097,152
#define WLO_OFF   35655680ull   // 2,097,152
#define WOT_OFF   37752832ull   // 50304*512*4    = 103,022,592

extern "C" void kernel_launch(void* const* d_in, const int* in_sizes, int n_in,
                              void* d_out, int out_size, void* d_ws, size_t ws_size,
                              hipStream_t stream) {
    (void)in_sizes; (void)n_in; (void)out_size; (void)ws_size;
    const int*   idx = (const int*)  d_in[0];
    const float* E   = (const float*)d_in[1];
    const float* Wi  = (const float*)d_in[2];
    const float* Wh  = (const float*)d_in[3];
    const float* bh  = (const float*)d_in[4];
    const float* Wo  = (const float*)d_in[5];
    const float* bo  = (const float*)d_in[6];
    float* out = (float*)d_out;
    char* ws = (char*)d_ws;

    unsigned short* xzH   = (unsigned short*)(ws + XZH_OFF);
    uint32_t*       hsP   = (uint32_t*)      (ws + HSP_OFF);
    uint32_t*       hsL   = (uint32_t*)      (ws + HSL_OFF);
    uint32_t*       flagL = (uint32_t*)      (ws + FLG_OFF);
    uint32_t*       flagM = (uint32_t*)      (ws + FLG_OFF + 512);
    uint32_t*       epC   = (uint32_t*)      (ws + FLG_OFF + 1024);
    uint32_t*       WHI   = (uint32_t*)      (ws + WHI_OFF);
    uint32_t*       WLO   = (uint32_t*)      (ws + WLO_OFF);
    uint32_t*       WoTP  = (uint32_t*)      (ws + WOT_OFF);

    // zero all sync flags each call (no cross-replay sync state)
    hipMemsetAsync(ws + FLG_OFF, 0, 4096, stream);

    hipLaunchKernelGGL(k0_wot,    dim3(25152), dim3(256), 0, stream, Wo, WoTP);
    hipLaunchKernelGGL(k0b_whfrag,dim3(512),   dim3(256), 0, stream, Wh, WHI, WLO);
    hipLaunchKernelGGL(k1_xz,     dim3(256),   dim3(256), 0, stream, idx, E, Wi, xzH);
    hipLaunchKernelGGL(k23,       dim3(256),   dim3(256), 0, stream,
                       bh, xzH, (const short8*)WHI, (const short8*)WLO, hsP, hsL,
                       flagL, flagM, epC, WoTP, bo, out);
}

// Round 11
// 3383.704 us; speedup vs baseline: 1.2384x; 1.2384x over previous
//
#include <hip/hip_runtime.h>
#include <cstdint>

// LSTM LM: logits = LSTM(E[idx] @ Wi) @ Wo + bo
// B=16, S=256, D=256, H=512, 4H=2048, V=50257 (padded to 50304 = 393*128)
//
// Round-11 = round-8 (best, 3.26ms k23) + two store/barrier fixes:
//  (1) coalesced h-publish: owner lanes -> LDS stage (2KB) -> syncthreads ->
//      128 threads issue 16B sc1 stores (128 txn/block vs r8's 512 scattered 4B).
//  (2) single-transition release barrier: arrive via RETURNING fetch_add; the
//      16th arriver stores rel=t+1 (and epC=t+1) once. Pollers see one clean
//      transition instead of a 16-increment counter ramp.
//  Producers: 16 blocks x 4 waves (vp = blk*4+w), r8 math verbatim.
//  Consumers: 240 blocks, r8 GEMM verbatim, gated on epC.
//  Liveness: roles from blockIdx only; last-arriver publishes epC=256 at t=255.

typedef __attribute__((ext_vector_type(8))) short short8;
typedef __attribute__((ext_vector_type(4))) float f32x4;
typedef __attribute__((ext_vector_type(4))) unsigned int u32x4;
typedef __attribute__((ext_vector_type(4))) unsigned short ush4;

#define DEVFN static __device__ __forceinline__

DEVFN unsigned short f2bf(float f) {
    unsigned int u = __float_as_uint(f);
    return (unsigned short)((u + 0x7FFFu + ((u >> 16) & 1u)) >> 16);  // RNE
}
DEVFN float bf2f(unsigned short h) { return __uint_as_float(((unsigned int)h) << 16); }
DEVFN float sigm(float x) { return 1.0f / (1.0f + __expf(-x)); }
DEVFN float tanh_fast(float x) {
    float e = __expf(-2.0f * fabsf(x));
    float t = (1.0f - e) / (1.0f + e);
    return copysignf(t, x);
}
DEVFN f32x4 fzero() { f32x4 v = {0.f, 0.f, 0.f, 0.f}; return v; }

// MALL-coherent (L1+L2 bypass) scalar flag load/store.
DEVFN uint32_t ld_flag_mall(const uint32_t* p) {
    uint32_t v;
    asm volatile("global_load_dword %0, %1, off sc0 sc1\n\ts_waitcnt vmcnt(0)"
                 : "=v"(v) : "v"(p) : "memory");
    return v;
}
DEVFN void st_flag_mall(uint32_t* p, uint32_t v) {
    asm volatile("global_store_dword %0, %1, off sc0 sc1" :: "v"(p), "v"(v) : "memory");
}
// 16B MALL-coherent ops (no embedded wait; batch + vmcnt(0) at call site).
DEVFN void aload16(u32x4& d, const void* p) {
    asm volatile("global_load_dwordx4 %0, %1, off sc0 sc1" : "=v"(d) : "v"(p));
}
DEVFN void astore16(uint32_t* p, u32x4 v) {
    asm volatile("global_store_dwordx4 %0, %1, off sc0 sc1" :: "v"(p), "v"(v) : "memory");
}

// ---------------- k0: transpose + split Wo -> WoTP[50304][512] packed u32 ----------------
__global__ __launch_bounds__(256) void k0_wot(const float* __restrict__ Wo,
                                              uint32_t* __restrict__ WoTP) {
    __shared__ float tile[32][33];
    const int bx = blockIdx.x;
    const int cb = bx >> 4;
    const int kb = bx & 15;
    const int c0 = cb * 32, k0 = kb * 32;
    const int j = threadIdx.x & 31;
    const int i0 = threadIdx.x >> 5;
    for (int ii = i0; ii < 32; ii += 8) {
        const int c = c0 + j;
        tile[ii][j] = (c < 50257) ? Wo[(size_t)(k0 + ii) * 50257 + c] : 0.0f;
    }
    __syncthreads();
    for (int ii = i0; ii < 32; ii += 8) {
        const float v = tile[j][ii];
        const unsigned short hi = f2bf(v);
        const unsigned short lo = f2bf(v - bf2f(hi));
        WoTP[(size_t)(c0 + ii) * 512 + k0 + j] = (((unsigned int)hi) << 16) | lo;
    }
}

// ---------------- k0b: Wh bf16-lo B-fragments: [vp][nt][q][lane] 16B each ----------------
__global__ __launch_bounds__(256) void k0b_whlo(const float* __restrict__ Wh,
                                                uint32_t* __restrict__ WLO) {
    const int tid = blockIdx.x * 256 + threadIdx.x;
    const int lane = tid & 63;
    const int q    = (tid >> 6) & 15;
    const int nt   = (tid >> 10) & 1;
    const int vp   = tid >> 11;          // virtual producer 0..63 (8 hidden units each)
    const int cc   = lane & 15;
    const int gcol = (cc >> 2) * 512 + vp * 8 + nt * 4 + (cc & 3);
    const int kbase = q * 32 + (lane >> 4) * 8;
    u32x4 o;
#pragma unroll
    for (int p = 0; p < 4; ++p) {
        unsigned int pair = 0;
#pragma unroll
        for (int e = 0; e < 2; ++e) {
            const int k = kbase + p * 2 + e;
            const float w = Wh[(size_t)k * 2048 + gcol];
            const unsigned short hi = f2bf(w);
            const unsigned short lo = f2bf(w - bf2f(hi));
            pair |= ((unsigned int)lo) << (e * 16);
        }
        o[p] = pair;
    }
    *(u32x4*)(WLO + (size_t)tid * 4) = o;
}

// ---------------- k1: xzH[s][b][g] = bf16( sum_d E[idx[b,s],d] * Wi[d,g] ) ---------------
__global__ __launch_bounds__(256) void k1_xz(const int* __restrict__ idx,
                                             const float* __restrict__ E,
                                             const float* __restrict__ Wi,
                                             unsigned short* __restrict__ xzH) {
    __shared__ float xs[16][256];
    const int s = blockIdx.x;
    const int t = threadIdx.x;
#pragma unroll
    for (int b = 0; b < 16; ++b) {
        const int row = idx[b * 256 + s];
        xs[b][t] = E[(size_t)row * 256 + t];
    }
    __syncthreads();
    for (int half = 0; half < 2; ++half) {
        const int g0 = half * 1024 + t * 4;
        f32x4 acc[16];
#pragma unroll
        for (int b = 0; b < 16; ++b) acc[b] = fzero();
        for (int d = 0; d < 256; ++d) {
            const f32x4 w = *(const f32x4*)&Wi[(size_t)d * 2048 + g0];
#pragma unroll
            for (int b = 0; b < 16; ++b) {
                const float xv = xs[b][d];
                acc[b] += xv * w;
            }
        }
#pragma unroll
        for (int b = 0; b < 16; ++b) {
            ush4 o;
#pragma unroll
            for (int jj = 0; jj < 4; ++jj) o[jj] = f2bf(acc[b][jj]);
            *(ush4*)&xzH[((size_t)s * 16 + b) * 2048 + g0] = o;
        }
    }
}

// ---------------- k23: fused recurrence (16 blocks) + consumer GEMM (240 blocks) ---------
__global__ __launch_bounds__(256, 1) void k23(const float* __restrict__ Wh,
                                              const float* __restrict__ bh,
                                              const unsigned short* __restrict__ xzH,
                                              const short8* __restrict__ WLO8,
                                              uint32_t* __restrict__ hsP,
                                              const uint32_t* __restrict__ zeroh,
                                              uint32_t* __restrict__ arrive,  // RMW counter
                                              uint32_t* __restrict__ rel,     // release word
                                              uint32_t* __restrict__ epC,     // consumer mirror
                                              const uint32_t* __restrict__ WoTP,
                                              const float* __restrict__ bo,
                                              float* __restrict__ out) {
    __shared__ __align__(16) char smem[131072];   // 128KB Wh-hi (producers) / GEMM tiles
    __shared__ __align__(16) uint32_t hstage[16][32];   // 2KB h publish stage

    const int tid = threadIdx.x;

    if (blockIdx.x < 16) {
        // ================= PRODUCER block: 4 frontier waves (vp = blk*4 + w) =============
        const int blk = blockIdx.x;

        // stage 4 Wh-hi slices (32KB each), r2's mapping per slice
        for (int vs = 0; vs < 4; ++vs) {
            const int vp_s = blk * 4 + vs;
            const int l = tid >> 3, seg = tid & 7;
            const int cc = l & 15, nt0 = l >> 4;
            const int gcol = (cc >> 2) * 512 + vp_s * 8 + nt0 * 4 + (cc & 3);
            for (int k8 = seg * 64; k8 < seg * 64 + 64; k8 += 8) {
                short8 v;
#pragma unroll
                for (int i = 0; i < 8; ++i)
                    v[i] = (short)f2bf(Wh[(size_t)(k8 + i) * 2048 + gcol]);
                const int slot = (k8 >> 3) ^ (l & 7);
                *(short8*)(smem + vs * 32768 + l * 1024 + slot * 16) = v;
            }
        }
        __syncthreads();

        const int w = tid >> 6;
        const int lane = tid & 63;
        const int vp = blk * 4 + w;
        unsigned short* whhW = (unsigned short*)(smem + w * 32768);
        const int c = lane & 15;
        const int qtr = lane >> 4;

        int gc[2];
        float bh_v[2];
#pragma unroll
        for (int nt = 0; nt < 2; ++nt) {
            gc[nt] = (c >> 2) * 512 + vp * 8 + nt * 4 + (c & 3);
            bh_v[nt] = bh[gc[nt]];
        }
        float cst[2][4];
#pragma unroll
        for (int nt = 0; nt < 2; ++nt)
#pragma unroll
            for (int r = 0; r < 4; ++r) cst[nt][r] = 0.0f;

        float xzv[2][4];
#pragma unroll
        for (int nt = 0; nt < 2; ++nt)
#pragma unroll
            for (int r = 0; r < 4; ++r)
                xzv[nt][r] = bf2f(xzH[(size_t)(qtr * 4 + r) * 2048 + gc[nt]]);

        short8 bz = {0, 0, 0, 0, 0, 0, 0, 0};
        f32x4 bd0 = fzero(), bd1 = fzero();

        for (int t = 0; t < 256; ++t) {
            if (t > 0) {
                // single-transition release poll (uniform addr: 1 req/wave)
                while (true) {
                    const uint32_t v = ld_flag_mall(rel);
                    if (v >= (uint32_t)t) break;
#pragma unroll
                    for (int i = 0; i < 2; ++i) {
                        bd0 = __builtin_amdgcn_mfma_f32_16x16x32_bf16(bz, bz, bd0, 0, 0, 0);
                        bd1 = __builtin_amdgcn_mfma_f32_16x16x32_bf16(bz, bz, bd1, 0, 0, 0);
                    }
                }
                __builtin_amdgcn_sched_barrier(0);
            }

            const uint32_t* hbase = (t == 0)
                ? (zeroh + (size_t)c * 512)
                : (hsP + ((size_t)(t - 1) * 16 + c) * 512);

            f32x4 acc[2][2];
#pragma unroll
            for (int nt = 0; nt < 2; ++nt) { acc[nt][0] = fzero(); acc[nt][1] = fzero(); }

#pragma unroll
            for (int q = 0; q < 16; ++q) {
                const int kb = q * 32 + qtr * 8;
                const unsigned long long* hb64 = (const unsigned long long*)(hbase + kb);
                unsigned long long d[4];
#pragma unroll
                for (int i = 0; i < 4; ++i)
                    d[i] = __hip_atomic_load(hb64 + i, __ATOMIC_RELAXED,
                                             __HIP_MEMORY_SCOPE_AGENT);
                short8 ahi, alo;
#pragma unroll
                for (int i = 0; i < 4; ++i) {
                    const uint32_t wlo32 = (uint32_t)d[i];
                    const uint32_t whi32 = (uint32_t)(d[i] >> 32);
                    ahi[2 * i]     = (short)(wlo32 >> 16); alo[2 * i]     = (short)(wlo32 & 0xffffu);
                    ahi[2 * i + 1] = (short)(whi32 >> 16); alo[2 * i + 1] = (short)(whi32 & 0xffffu);
                }
#pragma unroll
                for (int nt = 0; nt < 2; ++nt) {
                    const int l = nt * 16 + c;
                    const short8 bhi = *(const short8*)((const char*)whhW + l * 1024 +
                                                        (((q * 4 + qtr) ^ (l & 7)) << 4));
                    const short8 blo = WLO8[(((size_t)vp * 2 + nt) * 16 + q) * 64 + lane];
                    f32x4 a = acc[nt][q & 1];
                    a = __builtin_amdgcn_mfma_f32_16x16x32_bf16(ahi, bhi, a, 0, 0, 0);
                    a = __builtin_amdgcn_mfma_f32_16x16x32_bf16(ahi, blo, a, 0, 0, 0);
                    a = __builtin_amdgcn_mfma_f32_16x16x32_bf16(alo, bhi, a, 0, 0, 0);
                    acc[nt][q & 1] = a;
                }
            }

#pragma unroll
            for (int nt = 0; nt < 2; ++nt) {
                f32x4 z4 = acc[nt][0] + acc[nt][1];
#pragma unroll
                for (int r = 0; r < 4; ++r) z4[r] += xzv[nt][r] + bh_v[nt];
#pragma unroll
                for (int r = 0; r < 4; ++r) {
                    const int sb = (lane & 0x33);
                    const float zi = __shfl(z4[r], sb);
                    const float zf = __shfl(z4[r], sb | 4);
                    const float zg = __shfl(z4[r], sb | 8);
                    const float zo = __shfl(z4[r], sb | 12);
                    const float iv = sigm(zi), fv = sigm(zf);
                    const float gv = tanh_fast(zg), ov = sigm(zo);
                    const float cv = fv * cst[nt][r] + iv * gv;
                    cst[nt][r] = cv;
                    const float hv = ov * tanh_fast(cv);
                    if ((c >> 2) == 0) {   // one owner lane per (b, j): stage into LDS
                        const unsigned short hi = f2bf(hv);
                        const unsigned short lo = f2bf(hv - bf2f(hi));
                        hstage[qtr * 4 + r][w * 8 + nt * 4 + c] =
                            (((uint32_t)hi) << 16) | lo;
                    }
                }
            }

            // coalesced h-publish: 128 threads x 16B sc1 stores (4x fewer MALL txns)
            __syncthreads();
            if (tid < 128) {
                const int b = tid >> 3, ch = tid & 7;
                const u32x4 val = *(const u32x4*)&hstage[b][ch * 4];
                astore16(hsP + ((size_t)t * 16 + b) * 512 + blk * 32 + ch * 4, val);
            }
            asm volatile("s_waitcnt vmcnt(0)" ::: "memory");
            __syncthreads();

            // arrive; 16th arriver publishes the release (single transition)
            if (tid == 0) {
                const uint32_t old = __hip_atomic_fetch_add(arrive, 1u, __ATOMIC_RELAXED,
                                                            __HIP_MEMORY_SCOPE_AGENT);
                if (old == 16u * (uint32_t)(t + 1) - 1u) {
                    st_flag_mall(rel, (uint32_t)(t + 1));
                    st_flag_mall(epC, (uint32_t)(t + 1));
                }
            }

            if (t < 255) {
#pragma unroll
                for (int nt = 0; nt < 2; ++nt)
#pragma unroll
                    for (int r = 0; r < 4; ++r)
                        xzv[nt][r] = bf2f(xzH[((size_t)(t + 1) * 16 + qtr * 4 + r) * 2048 + gc[nt]]);
            }
        }
        asm volatile("" :: "v"(bd0), "v"(bd1));
    } else {
        // ================= CONSUMER (240 blocks): s0-outer / v-inner =====================
        unsigned short (*Ah)[64] = (unsigned short(*)[64])(smem);
        unsigned short (*Al)[64] = (unsigned short(*)[64])(smem + 16384);
        unsigned short (*Bh)[64] = (unsigned short(*)[64])(smem + 32768);
        unsigned short (*Bl)[64] = (unsigned short(*)[64])(smem + 49152);

        const int cid = blockIdx.x - 16;   // 0..239
        const int lane = tid & 63;
        const int wv = tid >> 6;
        const int wr = wv >> 1, wc = wv & 1;
        const int srow = tid >> 1, shalf = tid & 1;

        short8 bz = {0, 0, 0, 0, 0, 0, 0, 0};
        f32x4 bd0 = fzero(), bd1 = fzero(), bd2 = fzero(), bd3 = fzero();

        for (int s0 = 0; s0 < 32; ++s0) {
            const unsigned need = (unsigned)(s0 * 8 + 8);   // steps done required
            while (true) {
                const uint32_t f = ld_flag_mall(epC);       // uniform addr: 1 req/wave
                if (f >= need) break;
#pragma unroll
                for (int i = 0; i < 8; ++i) {
                    bd0 = __builtin_amdgcn_mfma_f32_16x16x32_bf16(bz, bz, bd0, 0, 0, 0);
                    bd1 = __builtin_amdgcn_mfma_f32_16x16x32_bf16(bz, bz, bd1, 0, 0, 0);
                    bd2 = __builtin_amdgcn_mfma_f32_16x16x32_bf16(bz, bz, bd2, 0, 0, 0);
                    bd3 = __builtin_amdgcn_mfma_f32_16x16x32_bf16(bz, bz, bd3, 0, 0, 0);
                }
            }

            for (int vi = 0; vi < 2; ++vi) {
                const int v = cid + vi * 240;
                if (v >= 393) break;

                f32x4 acc[4][4];
#pragma unroll
                for (int i = 0; i < 4; ++i)
#pragma unroll
                    for (int j = 0; j < 4; ++j) acc[i][j] = fzero();

                for (int kb = 0; kb < 8; ++kb) {
                    __syncthreads();
                    const uint32_t* sa = hsP + (size_t)(s0 * 128 + srow) * 512 + kb * 64 + shalf * 32;
                    const uint32_t* sbp = WoTP + (size_t)(v * 128 + srow) * 512 + kb * 64 + shalf * 32;
                    u32x4 av[8], bv[8];
#pragma unroll
                    for (int g = 0; g < 4; ++g) {
                        aload16(av[2 * g], sa + g * 8);
                        aload16(av[2 * g + 1], sa + g * 8 + 4);
                    }
#pragma unroll
                    for (int g = 0; g < 4; ++g) {
                        bv[2 * g]     = *(const u32x4*)(sbp + g * 8);
                        bv[2 * g + 1] = *(const u32x4*)(sbp + g * 8 + 4);
                    }
                    asm volatile("s_waitcnt vmcnt(0)" ::: "memory");
                    __builtin_amdgcn_sched_barrier(0);
#pragma unroll
                    for (int g = 0; g < 4; ++g) {
                        short8 hi, lo;
#pragma unroll
                        for (int i = 0; i < 4; ++i) {
                            hi[i]     = (short)(av[2 * g][i] >> 16);
                            lo[i]     = (short)(av[2 * g][i] & 0xffffu);
                            hi[4 + i] = (short)(av[2 * g + 1][i] >> 16);
                            lo[4 + i] = (short)(av[2 * g + 1][i] & 0xffffu);
                        }
                        const int sw = ((shalf * 4 + g) ^ (srow & 7)) << 4;
                        *(short8*)((char*)Ah + srow * 128 + sw) = hi;
                        *(short8*)((char*)Al + srow * 128 + sw) = lo;
                    }
#pragma unroll
                    for (int g = 0; g < 4; ++g) {
                        short8 hi, lo;
#pragma unroll
                        for (int i = 0; i < 4; ++i) {
                            hi[i]     = (short)(bv[2 * g][i] >> 16);
                            lo[i]     = (short)(bv[2 * g][i] & 0xffffu);
                            hi[4 + i] = (short)(bv[2 * g + 1][i] >> 16);
                            lo[4 + i] = (short)(bv[2 * g + 1][i] & 0xffffu);
                        }
                        const int sw = ((shalf * 4 + g) ^ (srow & 7)) << 4;
                        *(short8*)((char*)Bh + srow * 128 + sw) = hi;
                        *(short8*)((char*)Bl + srow * 128 + sw) = lo;
                    }
                    __syncthreads();

#pragma unroll
                    for (int q = 0; q < 2; ++q) {
                        short8 afh[4], afl[4], bfh[4], bfl[4];
#pragma unroll
                        for (int mi = 0; mi < 4; ++mi) {
                            const int r = wr * 64 + mi * 16 + (lane & 15);
                            const int sw = ((q * 4 + (lane >> 4)) ^ (r & 7)) << 4;
                            afh[mi] = *(const short8*)((const char*)Ah + r * 128 + sw);
                            afl[mi] = *(const short8*)((const char*)Al + r * 128 + sw);
                        }
#pragma unroll
                        for (int nj = 0; nj < 4; ++nj) {
                            const int r = wc * 64 + nj * 16 + (lane & 15);
                            const int sw = ((q * 4 + (lane >> 4)) ^ (r & 7)) << 4;
                            bfh[nj] = *(const short8*)((const char*)Bh + r * 128 + sw);
                            bfl[nj] = *(const short8*)((const char*)Bl + r * 128 + sw);
                        }
#pragma unroll
                        for (int mi = 0; mi < 4; ++mi)
#pragma unroll
                            for (int nj = 0; nj < 4; ++nj) {
                                f32x4 a = acc[mi][nj];
                                a = __builtin_amdgcn_mfma_f32_16x16x32_bf16(afh[mi], bfh[nj], a, 0, 0, 0);
                                a = __builtin_amdgcn_mfma_f32_16x16x32_bf16(afh[mi], bfl[nj], a, 0, 0, 0);
                                a = __builtin_amdgcn_mfma_f32_16x16x32_bf16(afl[mi], bfh[nj], a, 0, 0, 0);
                                acc[mi][nj] = a;
                            }
                    }
                }

#pragma unroll
                for (int nj = 0; nj < 4; ++nj) {
                    const int colg = v * 128 + wc * 64 + nj * 16 + (lane & 15);
                    if (colg < 50257) {
                        const float bov = bo[colg];
#pragma unroll
                        for (int mi = 0; mi < 4; ++mi)
#pragma unroll
                            for (int r = 0; r < 4; ++r) {
                                const int tr = wr * 64 + mi * 16 + (lane >> 4) * 4 + r;
                                const int ss = s0 * 8 + (tr >> 4);
                                const int bb = tr & 15;
                                out[((size_t)bb * 256 + ss) * 50257 + colg] = acc[mi][nj][r] + bov;
                            }
                    }
                }
            }
        }
        asm volatile("" :: "v"(bd0), "v"(bd1), "v"(bd2), "v"(bd3));
    }
}

// ---------------- launch ----------------------------------------------------------------
// Workspace (total ~130 MB <= proven-safe 147 MB):
#define XZH_OFF   0ull          // 256*16*2048*2  = 16,777,216  (bf16 xz)
#define HSP_OFF   16777216ull   // 256*16*512*4   =  8,388,608  (packed u32 h, t-major)
#define ZEROH_OFF 25165824ull   // 16*512*4       = 32,768
#define FLG_OFF   25198592ull   // 768 B: arrive @ +0, rel @ +128, epC @ +256
#define WLO_OFF   25199360ull   // 64*2*16*64*16  =  2,097,152
#define WOT_OFF   27296512ull   // 50304*512*4    = 103,022,592

extern "C" void kernel_launch(void* const* d_in, const int* in_sizes, int n_in,
                              void* d_out, int out_size, void* d_ws, size_t ws_size,
                              hipStream_t stream) {
    (void)in_sizes; (void)n_in; (void)out_size; (void)ws_size;
    const int*   idx = (const int*)  d_in[0];
    const float* E   = (const float*)d_in[1];
    const float* Wi  = (const float*)d_in[2];
    const float* Wh  = (const float*)d_in[3];
    const float* bh  = (const float*)d_in[4];
    const float* Wo  = (const float*)d_in[5];
    const float* bo  = (const float*)d_in[6];
    float* out = (float*)d_out;
    char* ws = (char*)d_ws;

    unsigned short* xzH    = (unsigned short*)(ws + XZH_OFF);
    uint32_t*       hsP    = (uint32_t*)      (ws + HSP_OFF);
    uint32_t*       zeroh  = (uint32_t*)      (ws + ZEROH_OFF);
    uint32_t*       arrive = (uint32_t*)      (ws + FLG_OFF);
    uint32_t*       rel    = (uint32_t*)      (ws + FLG_OFF + 128);
    uint32_t*       epC    = (uint32_t*)      (ws + FLG_OFF + 256);
    uint32_t*       WLO    = (uint32_t*)      (ws + WLO_OFF);
    uint32_t*       WoTP   = (uint32_t*)      (ws + WOT_OFF);

    // zero h(-1) block + sync words each call (contiguous 33,536 B region)
    hipMemsetAsync(ws + ZEROH_OFF, 0, 33536, stream);

    hipLaunchKernelGGL(k0_wot,   dim3(25152), dim3(256), 0, stream, Wo, WoTP);
    hipLaunchKernelGGL(k0b_whlo, dim3(512),   dim3(256), 0, stream, Wh, WLO);
    hipLaunchKernelGGL(k1_xz,    dim3(256),   dim3(256), 0, stream, idx, E, Wi, xzH);
    hipLaunchKernelGGL(k23,      dim3(256),   dim3(256), 0, stream,
                       Wh, bh, xzH, (const short8*)WLO, hsP, zeroh, arrive, rel, epC,
                       WoTP, bo, out);
}